// Round 12
// baseline (153.558 us; speedup 1.0000x reference)
//
#include <hip/hip_runtime.h>

typedef __attribute__((ext_vector_type(8))) short short8;
typedef __attribute__((ext_vector_type(4))) float float4v;

__device__ inline float bf2f(ushort u) {
    unsigned v = ((unsigned)u) << 16;
    return __builtin_bit_cast(float, v);
}
__device__ inline ushort f2bf(float f) {
    unsigned u = __builtin_bit_cast(unsigned, f);
    u += 0x7FFFu + ((u >> 16) & 1u);   // RNE
    return (ushort)(u >> 16);
}

// async global->LDS, 16B per lane; LDS dest = wave-uniform base + lane*16
__device__ inline void gload_lds16(const ushort* g, ushort* l) {
    __builtin_amdgcn_global_load_lds(
        (const __attribute__((address_space(1))) unsigned int*)g,
        (__attribute__((address_space(3))) unsigned int*)l,
        16, 0, 0);
}

// ---------------------------------------------------------------------------
// Kernel 1: hs fp32 -> bf16 [4096][1024]
// ---------------------------------------------------------------------------
__global__ __launch_bounds__(256) void convert_hs(
    const float* __restrict__ hs, ushort* __restrict__ hsb) {
    const size_t base = ((size_t)blockIdx.x * 256 + threadIdx.x) * 16;
    union { ushort u[16]; uint4 v[2]; } o;
#pragma unroll
    for (int q = 0; q < 4; ++q) {
        float4v f = *(const float4v*)(hs + base + q * 4);
#pragma unroll
        for (int j = 0; j < 4; ++j) o.u[q * 4 + j] = f2bf(f[j]);
    }
    *(uint4*)(hsb + base)     = o.v[0];
    *(uint4*)(hsb + base + 8) = o.v[1];
}

// ---------------------------------------------------------------------------
// Kernel 2: W fp32 [K][N] -> Wt bf16 [N][K] (transpose + downcast)
// ---------------------------------------------------------------------------
__global__ __launch_bounds__(256) void transpose_w(
    const float* __restrict__ Wq, const float* __restrict__ Wv,
    ushort* __restrict__ Wtq, ushort* __restrict__ Wtv) {
    __shared__ ushort tile[64][68];
    const float* W = blockIdx.z ? Wv : Wq;
    ushort* Wt     = blockIdx.z ? Wtv : Wtq;
    const int k0 = blockIdx.y * 64, n0 = blockIdx.x * 64;
    const int tid = threadIdx.x;
    const int rr = tid >> 4;
    const int cc = (tid & 15) * 4;
    union U4 { ushort u[4]; uint2 v; };
#pragma unroll
    for (int i = 0; i < 4; ++i) {
        int row = rr + i * 16;
        float4v f = *(const float4v*)(W + (size_t)(k0 + row) * 1024 + n0 + cc);
        U4 x;
#pragma unroll
        for (int j = 0; j < 4; ++j) x.u[j] = f2bf(f[j]);
        *(uint2*)&tile[row][cc] = x.v;
    }
    __syncthreads();
#pragma unroll
    for (int i = 0; i < 4; ++i) {
        int row = rr + i * 16;
        U4 o;
#pragma unroll
        for (int j = 0; j < 4; ++j) o.u[j] = tile[cc + j][row];
        *(uint2*)(Wt + (size_t)(n0 + row) * 1024 + k0 + cc) = o.v;
    }
}

// ---------------------------------------------------------------------------
// Kernel 3: C = hsb @ Wt^T + b -> [B][H][S][64] bf16. m97-style staging +
// coalesced epilogue (C via swizzled LDS, dwordx4 stores).
// ---------------------------------------------------------------------------
__global__ __launch_bounds__(256) void qv_gemm(
    const ushort* __restrict__ hsb,
    const ushort* __restrict__ Wtq, const ushort* __restrict__ Wtv,
    const float* __restrict__ bq, const float* __restrict__ bv,
    ushort* __restrict__ q_ws, ushort* __restrict__ v_ws) {
    __shared__ ushort S[2 * 128 * 64];       // Al | Bl, reused as C (32 KB)
    ushort* Al = S;
    ushort* Bl = S + 128 * 64;
    const ushort* Wt  = blockIdx.z ? Wtv : Wtq;
    const float* bias = blockIdx.z ? bv : bq;
    ushort* out       = blockIdx.z ? v_ws : q_ws;
    const int m0 = blockIdx.y * 128, n0 = blockIdx.x * 128;
    const int tid = threadIdx.x;
    const int wid = tid >> 6, lane = tid & 63;
    const int quad = lane >> 4, l16 = lane & 15;
    const int wm = (wid >> 1) * 64, wn = (wid & 1) * 64;
    const int rbase = 32 * wid;
    const int srow = lane >> 3, scol = (lane & 7) * 8;

    float4v acc[4][4] = {};

    for (int kt = 0; kt < 1024; kt += 64) {
        __syncthreads();
#pragma unroll
        for (int c8 = 0; c8 < 4; ++c8) {
            int row = rbase + c8 * 8;
            gload_lds16(hsb + (size_t)(m0 + row + srow) * 1024 + kt + scol,
                        &Al[row * 64]);
            gload_lds16(Wt + (size_t)(n0 + row + srow) * 1024 + kt + scol,
                        &Bl[row * 64]);
        }
        __syncthreads();
#pragma unroll
        for (int ks = 0; ks < 2; ++ks) {
            short8 af[4], bfr[4];
#pragma unroll
            for (int mt = 0; mt < 4; ++mt)
                af[mt] = *(const short8*)&Al[(wm + mt * 16 + l16) * 64 + (ks * 4 + quad) * 8];
#pragma unroll
            for (int nt = 0; nt < 4; ++nt)
                bfr[nt] = *(const short8*)&Bl[(wn + nt * 16 + l16) * 64 + (ks * 4 + quad) * 8];
#pragma unroll
            for (int mt = 0; mt < 4; ++mt)
#pragma unroll
                for (int nt = 0; nt < 4; ++nt)
                    acc[mt][nt] = __builtin_amdgcn_mfma_f32_16x16x32_bf16(
                        af[mt], bfr[nt], acc[mt][nt], 0, 0, 0);
        }
    }
    __syncthreads();   // K-loop LDS reads done; S becomes C tile 128x128 (swz)
#pragma unroll
    for (int mt = 0; mt < 4; ++mt) {
#pragma unroll
        for (int nt = 0; nt < 4; ++nt) {
            int col = wn + nt * 16 + l16;
            float bsv = bias[n0 + col];
#pragma unroll
            for (int reg = 0; reg < 4; ++reg) {
                int row = wm + mt * 16 + quad * 4 + reg;
                S[row * 128 + (((col >> 3) ^ (row & 15)) << 3) + (col & 7)] =
                    f2bf(acc[mt][nt][reg] + bsv);
            }
        }
    }
    __syncthreads();
    {
        int row = tid >> 1, half = tid & 1;
        int r = m0 + row;
        int bb = r >> 11, s = r & 2047;
        int hh = (n0 >> 6) + half;
        ushort* dst = out + (((size_t)bb * 16 + hh) * 2048 + s) * 64;
#pragma unroll
        for (int c8 = 0; c8 < 8; ++c8) {
            int chunk = half * 8 + c8;
            *(uint4*)(dst + c8 * 8) =
                *(const uint4*)&S[row * 128 + ((chunk ^ (row & 15)) << 3)];
        }
    }
}

// ---------------------------------------------------------------------------
// Kernel 4: MFMA fused sparse attention v4. 512 threads, 128x256 tile,
// 73.5 KB LDS (2 blocks/CU). Band-aware wave-uniform guards: QK 9/16 tiles,
// PV 5/8 K-chunks (skipped work is exactly masked/zero -> bit-identical).
// ---------------------------------------------------------------------------
__global__ __launch_bounds__(512, 4) void attn(
    const ushort* __restrict__ q_ws, const ushort* __restrict__ v_ws,
    const float* __restrict__ amask, float* __restrict__ out) {
    const int t = blockIdx.x, h = blockIdx.y, b = blockIdx.z;

    __shared__ ushort KwPl[16384];   // Kw 256x64 (swz) -> later P-half 128x128 (swz)
    __shared__ ushort VtS[16384];    // V^T 64x256 (swz) -> later ctxp 128x64 fp32 (swz)
    __shared__ float  Sstr[128][17];
    __shared__ float  amw[256];

    const int tid = threadIdx.x;
    const int wid = tid >> 6, lane = tid & 63;
    const int quad = lane >> 4, l16 = lane & 15;
    const int r0 = wid * 16;
    const size_t qbase = ((size_t)b * 16 + h) * 2048 * 64;
    const int base_row = (t - 1) * 128;
    const int nk = (t >= 2) ? (t - 1) : 0;
    const int lo = wid & ~1;                       // touched P col-tiles [lo, lo+9]
    const int cklo = wid >> 1;                     // needed PV K-chunks (32 wide)
    const int ckhi = (wid * 16 + 143) >> 5;

    // ---- stage ----
    if (tid < 256) {
        int j = base_row + tid; if (j < 0) j = 0;
        amw[tid] = amask[(size_t)b * 2048 + j];
    }
#pragma unroll
    for (int i = 0; i < 4; ++i) {
        int u = tid + i * 512;
        int row = u >> 3, c = u & 7;
        int jg = base_row + row; if (jg < 0) jg = 0;
        *(uint4*)&KwPl[row * 64 + ((c ^ (row & 7)) * 8)] =
            *(const uint4*)(q_ws + qbase + (size_t)jg * 64 + c * 8);
    }
    {   // Vt via b64 register transpose: tid -> j0=(tid&63)*4, d0=(tid>>6)*8
        int j0 = (tid & 63) * 4, d0 = (tid >> 6) * 8;
        ushort vreg[4][8];
#pragma unroll
        for (int jj = 0; jj < 4; ++jj) {
            int jg = base_row + j0 + jj; if (jg < 0) jg = 0;
            *(uint4*)vreg[jj] = *(const uint4*)(v_ws + qbase + (size_t)jg * 64 + d0);
        }
        int cj = j0 >> 3, j7 = j0 & 7;
#pragma unroll
        for (int dd8 = 0; dd8 < 8; ++dd8) {
            int dd = d0 + dd8;
            union { ushort u4[4]; uint2 v; } pk;
            pk.u4[0] = vreg[0][dd8]; pk.u4[1] = vreg[1][dd8];
            pk.u4[2] = vreg[2][dd8]; pk.u4[3] = vreg[3][dd8];
            *(uint2*)&VtS[dd * 256 + ((cj ^ (dd & 7)) * 8) + j7] = pk.v;
        }
    }
    __syncthreads();

    // ---- QK^T: only col-tiles nt in [wid, wid+8] intersect the band ----
    float4v sacc[16] = {};
#pragma unroll
    for (int ks = 0; ks < 2; ++ks) {
        int c = ks * 4 + quad;
        int sw = (c ^ (l16 & 7)) * 8;
        short8 af = *(const short8*)&KwPl[(128 + r0 + l16) * 64 + sw];
#pragma unroll
        for (int nt = 0; nt < 16; ++nt) {
            if (nt >= wid && nt <= wid + 8) {
                short8 bfr = *(const short8*)&KwPl[(nt * 16 + l16) * 64 + sw];
                sacc[nt] = __builtin_amdgcn_mfma_f32_16x16x32_bf16(af, bfr, sacc[nt], 0, 0, 0);
            }
        }
    }

    // ---- strided scores: 4 lanes/row, 16-d quarters ----
    const int sr = tid >> 2;
    const int dq = (tid & 3) * 16;
    if (nk > 0) {
        float qv[16];
#pragma unroll
        for (int cc = 0; cc < 2; ++cc) {
            int c = (dq >> 3) + cc;
            union { uint4 v; ushort u[8]; } tm;
            tm.v = *(const uint4*)&KwPl[(128 + sr) * 64 + ((c ^ (sr & 7)) * 8)];
#pragma unroll
            for (int jj = 0; jj < 8; ++jj) qv[cc * 8 + jj] = bf2f(tm.u[jj]);
        }
        for (int k = 0; k < nk; ++k) {
            const ushort* kr = q_ws + qbase + (size_t)(sr + (k << 7)) * 64 + dq;
            float p = 0.f;
#pragma unroll
            for (int d = 0; d < 16; d += 8) {
                union { uint4 v; ushort u[8]; } tm;
                tm.v = *(const uint4*)(kr + d);
#pragma unroll
                for (int jj = 0; jj < 8; ++jj) p += qv[d + jj] * bf2f(tm.u[jj]);
            }
            p += __shfl_xor(p, 1);
            p += __shfl_xor(p, 2);
            if ((tid & 3) == 0)
                Sstr[sr][k] = p * 0.125f + amask[(size_t)b * 2048 + sr + (k << 7)];
        }
    }
    __syncthreads();   // Kw dead; region becomes P-half

    // ---- softmax; write P-half1 (touched tiles only), stash half2 ----
    unsigned pb[4][4];
#pragma unroll
    for (int reg = 0; reg < 4; ++reg) {
        int rr = r0 + quad * 4 + reg;
        float sv[16];
#pragma unroll
        for (int nt = 0; nt < 16; ++nt) {
            if (nt >= wid && nt <= wid + 8) {
                int c = nt * 16 + l16;
                bool allowed = (c >= rr) && (c <= rr + 128) && (t > 0 || c >= 128);
                sv[nt] = allowed ? sacc[nt][reg] * 0.125f + amw[c] : -INFINITY;
            } else sv[nt] = -INFINITY;
        }
        float sstr_v = (l16 < nk) ? Sstr[rr][l16] : -INFINITY;
        float m = sstr_v;
#pragma unroll
        for (int nt = 0; nt < 16; ++nt) m = fmaxf(m, sv[nt]);
#pragma unroll
        for (int off = 1; off < 16; off <<= 1) m = fmaxf(m, __shfl_xor(m, off));

        float es = (l16 < nk) ? __expf(sstr_v - m) : 0.f;
        float sum = es;
#pragma unroll
        for (int nt = 0; nt < 16; ++nt) {
            float e = (sv[nt] == -INFINITY) ? 0.f : __expf(sv[nt] - m);
            sv[nt] = e; sum += e;
        }
#pragma unroll
        for (int off = 1; off < 16; off <<= 1) sum += __shfl_xor(sum, off);
        float rden = 1.f / sum;
        // half1 writes: nt in [lo, lo+9] ∩ [0,8)
#pragma unroll
        for (int nt = 0; nt < 8; ++nt) {
            if (nt >= lo && nt <= lo + 9) {
                int c = nt * 2 + (l16 >> 3);
                KwPl[rr * 128 + ((c ^ (rr & 15)) * 8) + (l16 & 7)] = f2bf(sv[nt] * rden);
            }
        }
        // half2 stash
#pragma unroll
        for (int i2 = 0; i2 < 4; ++i2) {
            unsigned plo = f2bf(sv[8 + 2 * i2] * rden);
            unsigned phi = f2bf(sv[9 + 2 * i2] * rden);
            pb[reg][i2] = plo | (phi << 16);
        }
        if (l16 < nk) Sstr[rr][l16] = es * rden;
    }
    __syncthreads();

    // ---- PV pass 1: K-chunks ck=ks in [cklo, ckhi] ----
    float4v cacc[4] = {};
#pragma unroll
    for (int ks = 0; ks < 4; ++ks) {
        if (ks >= cklo && ks <= ckhi) {
            int cp = ks * 4 + quad;
            short8 af = *(const short8*)&KwPl[(r0 + l16) * 128 + ((cp ^ l16) * 8)];
#pragma unroll
            for (int nt = 0; nt < 4; ++nt) {
                int sw = (cp ^ (l16 & 7)) * 8;
                short8 bfr = *(const short8*)&VtS[(nt * 16 + l16) * 256 + sw];
                cacc[nt] = __builtin_amdgcn_mfma_f32_16x16x32_bf16(af, bfr, cacc[nt], 0, 0, 0);
            }
        }
    }
    __syncthreads();

    // ---- write P-half2 (touched tiles only) ----
#pragma unroll
    for (int reg = 0; reg < 4; ++reg) {
        int rr = r0 + quad * 4 + reg;
#pragma unroll
        for (int i2 = 0; i2 < 4; ++i2) {
#pragma unroll
            for (int e2 = 0; e2 < 2; ++e2) {
                int nt = 8 + 2 * i2 + e2;
                if (nt >= lo && nt <= lo + 9) {
                    int c = (nt - 8) * 2 + (l16 >> 3);
                    ushort val = (ushort)((pb[reg][i2] >> (16 * e2)) & 0xFFFF);
                    KwPl[rr * 128 + ((c ^ (rr & 15)) * 8) + (l16 & 7)] = val;
                }
            }
        }
    }
    __syncthreads();

    // ---- PV pass 2: K-chunks ck=4+ks in [cklo, ckhi] ----
#pragma unroll
    for (int ks = 0; ks < 4; ++ks) {
        if (4 + ks >= cklo && 4 + ks <= ckhi) {
            int cp = ks * 4 + quad;
            short8 af = *(const short8*)&KwPl[(r0 + l16) * 128 + ((cp ^ l16) * 8)];
#pragma unroll
            for (int nt = 0; nt < 4; ++nt) {
                int cv = 16 + cp;
                int sw = (cv ^ (l16 & 7)) * 8;
                short8 bfr = *(const short8*)&VtS[(nt * 16 + l16) * 256 + sw];
                cacc[nt] = __builtin_amdgcn_mfma_f32_16x16x32_bf16(af, bfr, cacc[nt], 0, 0, 0);
            }
        }
    }
    __syncthreads();   // Vt reads done; region becomes ctxp

    // ---- strided PV: 4 lanes/row -> ctxp (alias Vt) ----
    float* ctxp = (float*)&VtS[0];   // [128][64] fp32, chunk-swizzled
    {
        float acc16[16] = {};
        for (int k = 0; k < nk; ++k) {
            float p = Sstr[sr][k];
            const ushort* vr = v_ws + qbase + (size_t)(sr + (k << 7)) * 64 + dq;
#pragma unroll
            for (int d = 0; d < 16; d += 8) {
                union { uint4 v; ushort u[8]; } tm;
                tm.v = *(const uint4*)(vr + d);
#pragma unroll
                for (int jj = 0; jj < 8; ++jj) acc16[d + jj] += p * bf2f(tm.u[jj]);
            }
        }
#pragma unroll
        for (int d4 = 0; d4 < 4; ++d4) {
            int c = (dq >> 2) + d4;
            *(float4v*)&ctxp[sr * 64 + ((c ^ (sr & 15)) * 4)] =
                *(const float4v*)&acc16[d4 * 4];
        }
    }
    __syncthreads();

    // ---- epilogue: out[b][s][h*64+d], fp32 ----
    const size_t obase = ((size_t)b * 2048 + (size_t)t * 128) * 1024 + (size_t)h * 64;
#pragma unroll
    for (int nt = 0; nt < 4; ++nt)
#pragma unroll
        for (int reg = 0; reg < 4; ++reg) {
            int rr = r0 + quad * 4 + reg;
            int d = nt * 16 + l16;
            float cstr = ctxp[rr * 64 + (((d >> 2) ^ (rr & 15)) * 4) + (d & 3)];
            out[obase + (size_t)rr * 1024 + d] = cacc[nt][reg] + cstr;
        }
}

// ---------------------------------------------------------------------------
extern "C" void kernel_launch(void* const* d_in, const int* in_sizes, int n_in,
                              void* d_out, int out_size, void* d_ws, size_t ws_size,
                              hipStream_t stream) {
    int ihs = -1, iam = -1, iw1 = -1, iw2 = -1, ib1 = -1, ib2 = -1;
    for (int i = 0; i < n_in; ++i) {
        int s = in_sizes[i];
        if      (s == 4194304) { if (ihs < 0) ihs = i; }
        else if (s == 4096)    { if (iam < 0) iam = i; }
        else if (s == 1048576) { if (iw1 < 0) iw1 = i; else if (iw2 < 0) iw2 = i; }
        else if (s == 1024)    { if (ib1 < 0) ib1 = i; else if (ib2 < 0) ib2 = i; }
    }
    if (ihs < 0) ihs = 0; if (iam < 0) iam = 1;
    if (iw1 < 0) iw1 = 2; if (ib1 < 0) ib1 = 3;
    if (iw2 < 0) iw2 = 4; if (ib2 < 0) ib2 = 5;

    const float* hs    = (const float*)d_in[ihs];
    const float* amask = (const float*)d_in[iam];
    const float* Wq    = (const float*)d_in[iw1];
    const float* bq    = (const float*)d_in[ib1];
    const float* Wv    = (const float*)d_in[iw2];
    const float* bv    = (const float*)d_in[ib2];
    float* out = (float*)d_out;

    char* ws = (char*)d_ws;
    ushort* Wtq  = (ushort*)(ws);                           // 2 MB
    ushort* Wtv  = (ushort*)(ws + (1u << 21));              // 2 MB
    ushort* hsb  = (ushort*)(ws + (2u << 21));              // 8 MB
    ushort* q_ws = (ushort*)(ws + (2u << 21) + (1u << 23)); // 8 MB
    ushort* v_ws = (ushort*)(ws + (2u << 21) + (2u << 23)); // 8 MB

    convert_hs<<<1024, 256, 0, stream>>>(hs, hsb);
    transpose_w<<<dim3(16, 16, 2), 256, 0, stream>>>(Wq, Wv, Wtq, Wtv);
    qv_gemm<<<dim3(8, 32, 2), 256, 0, stream>>>(hsb, Wtq, Wtv, bq, bv, q_ws, v_ws);
    attn<<<dim3(16, 16, 2), 512, 0, stream>>>(q_ws, v_ws, amask, out);
}